// Round 3
// baseline (251.787 us; speedup 1.0000x reference)
//
#include <hip/hip_runtime.h>
#include <hip/hip_bf16.h>
#include <cstdint>
#include <cstddef>

// ---------------- types ----------------
typedef __bf16 bf16x8 __attribute__((ext_vector_type(8)));
typedef float f32x4 __attribute__((ext_vector_type(4)));
typedef float f32x16 __attribute__((ext_vector_type(16)));
typedef unsigned short u16x8 __attribute__((ext_vector_type(8)));
typedef unsigned short u16x4 __attribute__((ext_vector_type(4)));

#define S_LEN 2048
#define DMODEL 2048
#define NHEADS 16
#define HD 128

__device__ inline unsigned short f2bf(float f) {
  union { float f; unsigned int u; } v; v.f = f;
  unsigned int r = (v.u + 0x7fffu + ((v.u >> 16) & 1u)) >> 16;
  return (unsigned short)r;
}

// async global->LDS, 16B per lane; LDS dest = wave-uniform base + lane*16
__device__ __forceinline__ void gload16(const unsigned short* g,
                                        unsigned short* lds) {
  __builtin_amdgcn_global_load_lds(
      (const __attribute__((address_space(1))) void*)g,
      (__attribute__((address_space(3))) void*)lds, 16, 0, 0);
}

// ---------------- fused cast fp32 -> bf16 (all 5 matrices, 1 dispatch) -----
__global__ void cast_all(const float* __restrict__ x, const float* __restrict__ wq,
                         const float* __restrict__ wk, const float* __restrict__ wv,
                         const float* __restrict__ wo,
                         unsigned short* __restrict__ out, float qscale) {
  const int b = blockIdx.x;
  const int seg = b >> 12;                       // 4096 blocks per segment
  const int i = ((b & 4095) * 256 + threadIdx.x) * 4;
  const float* src = seg == 0 ? x : seg == 1 ? wq : seg == 2 ? wk
                   : seg == 3 ? wv : wo;
  const float scale = (seg == 1) ? qscale : 1.0f;
  unsigned short* dst = out + (size_t)seg * ((size_t)S_LEN * DMODEL);
  float4 v = *(const float4*)(src + i);
  u16x4 o;
  o.x = f2bf(v.x * scale); o.y = f2bf(v.y * scale);
  o.z = f2bf(v.z * scale); o.w = f2bf(v.w * scale);
  *(u16x4*)(dst + i) = o;
}

// ---------------- GEMM core: C[M,N] = A[M,K] * B[N,K]^T (bf16, fp32 acc) ---
// BK=64, XOR column-chunk swizzle staging.
// MODE 1: bf16 out   MODE 2: bf16 out transposed (C^T)
template <int MODE>
__device__ __forceinline__ void gemm_core64(
    const unsigned short* __restrict__ A, const unsigned short* __restrict__ B,
    unsigned short* __restrict__ Cb,
    int M, int N, int K, int m0, int n0,
    unsigned short* As, unsigned short* Bs) {
  constexpr int BK = 64;
  const int tid = threadIdx.x;
  const int wave = tid >> 6, lane = tid & 63;
  const int lg = lane >> 4, lr = lane & 15;
  const int rw = (wave >> 1) * 64;
  const int cw = (wave & 1) * 64;
  const int swz = lr & 7;

  const unsigned short* Ap[4];
  const unsigned short* Bp[4];
  unsigned short *as[4], *bs[4];
#pragma unroll
  for (int j = 0; j < 4; j++) {
    const int cc = j * 256 + tid;
    const int row = cc >> 3;
    const int col8 = (cc & 7) ^ (row & 7);       // XOR swizzle
    Ap[j] = A + (size_t)(m0 + row) * K + col8 * 8;
    Bp[j] = B + (size_t)(n0 + row) * K + col8 * 8;
    as[j] = As + j * 2048 + wave * 512;
    bs[j] = Bs + j * 2048 + wave * 512;
  }

  f32x4 acc[4][4];
#pragma unroll
  for (int i = 0; i < 4; i++)
#pragma unroll
    for (int j = 0; j < 4; j++) acc[i][j] = (f32x4){0.f, 0.f, 0.f, 0.f};

  const int nk = K / BK;
  for (int kt = 0; kt < nk; ++kt) {
    const int ko = kt * BK;
    __syncthreads();
#pragma unroll
    for (int j = 0; j < 4; j++) {
      gload16(Ap[j] + ko, as[j]);
      gload16(Bp[j] + ko, bs[j]);
    }
    __syncthreads();

#pragma unroll
    for (int kk = 0; kk < 2; kk++) {
      bf16x8 af[4], bfr[4];
#pragma unroll
      for (int mt = 0; mt < 4; mt++)
        af[mt] = *(const bf16x8*)(As + (rw + mt * 16 + lr) * 64 +
                                  (((kk * 4 + lg) ^ swz) * 8));
#pragma unroll
      for (int nt = 0; nt < 4; nt++)
        bfr[nt] = *(const bf16x8*)(Bs + (cw + nt * 16 + lr) * 64 +
                                   (((kk * 4 + lg) ^ swz) * 8));
#pragma unroll
      for (int mt = 0; mt < 4; mt++)
#pragma unroll
        for (int nt = 0; nt < 4; nt++)
          acc[mt][nt] = __builtin_amdgcn_mfma_f32_16x16x32_bf16(
              af[mt], bfr[nt], acc[mt][nt], 0, 0, 0);
    }
  }

#pragma unroll
  for (int mt = 0; mt < 4; mt++)
#pragma unroll
    for (int nt = 0; nt < 4; nt++) {
      const int col = n0 + cw + nt * 16 + lr;
#pragma unroll
      for (int r = 0; r < 4; r++) {
        const int row = m0 + rw + mt * 16 + lg * 4 + r;
        const float v = acc[mt][nt][r];
        if (MODE == 1) Cb[(size_t)row * N + col] = f2bf(v);
        else Cb[(size_t)col * M + row] = f2bf(v);
      }
    }
}

// fused Q/K/V projection: grid (48, 16); blockIdx.x>>4 selects weight/output
__global__ __launch_bounds__(256, 2) void gemm_qkv(
    const unsigned short* __restrict__ xb, const unsigned short* __restrict__ wqb,
    const unsigned short* __restrict__ wkb, const unsigned short* __restrict__ wvb,
    unsigned short* __restrict__ qb, unsigned short* __restrict__ kb,
    unsigned short* __restrict__ vTb) {
  __shared__ unsigned short As[128 * 64];
  __shared__ unsigned short Bs[128 * 64];
  const int which = blockIdx.x >> 4;             // block-uniform
  const int n0 = (blockIdx.x & 15) * 128;
  const int m0 = blockIdx.y * 128;
  if (which == 0)
    gemm_core64<1>(xb, wqb, qb, S_LEN, DMODEL, DMODEL, m0, n0, As, Bs);
  else if (which == 1)
    gemm_core64<1>(xb, wkb, kb, S_LEN, DMODEL, DMODEL, m0, n0, As, Bs);
  else
    gemm_core64<2>(xb, wvb, vTb, S_LEN, DMODEL, DMODEL, m0, n0, As, Bs);
}

// ---------------- O-projection GEMM, 64x128 tile, BK=128, fp32 out --------
__global__ __launch_bounds__(256, 2) void gemm_bt64(
    const unsigned short* __restrict__ A, const unsigned short* __restrict__ B,
    float* __restrict__ Cf, int M, int N, int K) {
  constexpr int BK = 128;
  __shared__ unsigned short As[64 * 128];
  __shared__ unsigned short Bs[128 * 128];
  const int tid = threadIdx.x;
  const int wave = tid >> 6, lane = tid & 63;
  const int lg = lane >> 4, lr = lane & 15;
  const int rw = (wave >> 1) * 32;
  const int cw = (wave & 1) * 64;
  const int m0 = blockIdx.y * 64, n0 = blockIdx.x * 128;
  const int swz = lr & 7;

  const unsigned short* Ap[4];
  const unsigned short* Bp[8];
  unsigned short *as[4], *bs[8];
#pragma unroll
  for (int j = 0; j < 4; j++) {
    const int cc = j * 256 + tid;
    const int row = cc >> 4;
    const int col16 = (cc & 15) ^ (row & 7);
    Ap[j] = A + (size_t)(m0 + row) * K + col16 * 8;
    as[j] = As + j * 2048 + wave * 512;
  }
#pragma unroll
  for (int j = 0; j < 8; j++) {
    const int cc = j * 256 + tid;
    const int row = cc >> 4;
    const int col16 = (cc & 15) ^ (row & 7);
    Bp[j] = B + (size_t)(n0 + row) * K + col16 * 8;
    bs[j] = Bs + j * 2048 + wave * 512;
  }

  f32x4 acc[2][4];
#pragma unroll
  for (int i = 0; i < 2; i++)
#pragma unroll
    for (int j = 0; j < 4; j++) acc[i][j] = (f32x4){0.f, 0.f, 0.f, 0.f};

  const int nk = K / BK;
  for (int kt = 0; kt < nk; ++kt) {
    const int ko = kt * BK;
    __syncthreads();
#pragma unroll
    for (int j = 0; j < 4; j++) gload16(Ap[j] + ko, as[j]);
#pragma unroll
    for (int j = 0; j < 8; j++) gload16(Bp[j] + ko, bs[j]);
    __syncthreads();

#pragma unroll
    for (int kk = 0; kk < 4; kk++) {
      bf16x8 af[2], bfr[4];
#pragma unroll
      for (int mt = 0; mt < 2; mt++)
        af[mt] = *(const bf16x8*)(As + (rw + mt * 16 + lr) * 128 +
                                  (((kk * 4 + lg) ^ swz) * 8));
#pragma unroll
      for (int nt = 0; nt < 4; nt++)
        bfr[nt] = *(const bf16x8*)(Bs + (cw + nt * 16 + lr) * 128 +
                                   (((kk * 4 + lg) ^ swz) * 8));
#pragma unroll
      for (int mt = 0; mt < 2; mt++)
#pragma unroll
        for (int nt = 0; nt < 4; nt++)
          acc[mt][nt] = __builtin_amdgcn_mfma_f32_16x16x32_bf16(
              af[mt], bfr[nt], acc[mt][nt], 0, 0, 0);
    }
  }

#pragma unroll
  for (int mt = 0; mt < 2; mt++)
#pragma unroll
    for (int nt = 0; nt < 4; nt++) {
      const int col = n0 + cw + nt * 16 + lr;
#pragma unroll
      for (int r = 0; r < 4; r++) {
        const int row = m0 + rw + mt * 16 + lg * 4 + r;
        Cf[(size_t)row * N + col] = acc[mt][nt][r];
      }
    }
}

// ---------------- flash attention, round 8: in-register P, 1 barrier/tile --
// S^T = K*Q^T per wave (32 keys x 32 queries, key axis register-local).
// P = exp2(S^T) stays IN REGISTER: v_cvt_pk_bf16_f32 pairs + v_permlane32_swap
// redistribute P across the lh halves into exact PV B-fragments (T12).
// Each wave accumulates a PARTIAL O^T over its own 32-key half across all
// 128 dims; the two kh-halves are summed once in the epilogue via LDS.
// Ks and Vt both double-buffered -> ONE barrier per tile; staging global
// loads issued at tile top, LDS writes at tile end (full-tile latency slack).
// XOR chunk swizzle (chunk ^= row&7) on Ks/Vt write+read: 4-way -> <=2-way
// bank conflicts (2-way is free, m136).
__global__ __launch_bounds__(256, 2) void attn_kernel(
    const unsigned short* __restrict__ q, const unsigned short* __restrict__ k,
    const unsigned short* __restrict__ vT, unsigned short* __restrict__ o) {
  constexpr int KT = 64;
  __shared__ unsigned short Ks[2][64 * 136];  // dbuf [key][dim: 16 chunks + pad]
  __shared__ unsigned short Vt[2][128 * 72];  // dbuf [dim][key: 8 chunks + pad]
  __shared__ float Lred[4][32];

  const int tid = threadIdx.x;
  const int w = tid >> 6, lane = tid & 63;
  const int l32 = lane & 31, lh = lane >> 5;
  const int l7 = l32 & 7;
  const int qh = w >> 1;     // query half
  const int kh = w & 1;      // key half (S^T and PV partial)
  const int h = blockIdx.y;
  const int q0 = blockIdx.x * 64;

  // Q as B-fragments in registers: B[k=d][n=q]
  bf16x8 qf[8];
#pragma unroll
  for (int ks = 0; ks < 8; ks++)
    qf[ks] = *(const bf16x8*)(q + (size_t)(q0 + qh * 32 + l32) * DMODEL +
                              h * HD + ks * 16 + lh * 8);

  // partial O^T over this wave's key half: [mt 4 dims-of-32][16 regs]
  f32x16 Oacc[4];
#pragma unroll
  for (int mt = 0; mt < 4; mt++)
#pragma unroll
    for (int j = 0; j < 16; j++) Oacc[mt][j] = 0.f;
  f32x4 lsumv = (f32x4){0.f, 0.f, 0.f, 0.f};

  // staging coordinates (+ swizzled LDS store offsets)
  int krow[4], kcg[4], vrow[4], vcg[4], kso[4], vso[4];
#pragma unroll
  for (int i = 0; i < 4; i++) {
    const int c = i * 256 + tid;
    krow[i] = c >> 4; kcg[i] = c & 15;
    vrow[i] = c >> 3; vcg[i] = c & 7;
    kso[i] = krow[i] * 136 + (kcg[i] ^ (krow[i] & 7)) * 8;
    vso[i] = vrow[i] * 72 + (vcg[i] ^ (vrow[i] & 7)) * 8;
  }

  // swizzled LDS read offsets (loop-invariant)
  int kfo[8];
#pragma unroll
  for (int ks = 0; ks < 8; ks++)
    kfo[ks] = (kh * 32 + l32) * 136 + (((ks * 2 + lh) ^ l7) * 8);
  int vfo[4][2];
#pragma unroll
  for (int mt = 0; mt < 4; mt++)
#pragma unroll
    for (int s = 0; s < 2; s++)
      vfo[mt][s] = (mt * 32 + l32) * 72 + (((kh * 4 + s * 2 + lh) ^ l7) * 8);

  // prologue: tile 0 -> regs -> LDS[0]
  u16x8 kreg[4], vreg[4];
#pragma unroll
  for (int i = 0; i < 4; i++) {
    kreg[i] = *(const u16x8*)(k + (size_t)(krow[i]) * DMODEL + h * HD + kcg[i] * 8);
    vreg[i] = *(const u16x8*)(vT + (size_t)(h * HD + vrow[i]) * S_LEN + vcg[i] * 8);
  }
#pragma unroll
  for (int i = 0; i < 4; i++) {
    *(u16x8*)(Ks[0] + kso[i]) = kreg[i];
    *(u16x8*)(Vt[0] + vso[i]) = vreg[i];
  }
  __syncthreads();

  constexpr int NT = S_LEN / KT;
  for (int kt = 0; kt < NT; ++kt) {
    // issue next-tile global loads (consumed at tile end -> full-tile slack)
    if (kt + 1 < NT) {
      const int kbase = (kt + 1) * KT;
#pragma unroll
      for (int i = 0; i < 4; i++) {
        kreg[i] = *(const u16x8*)(k + (size_t)(kbase + krow[i]) * DMODEL +
                                  h * HD + kcg[i] * 8);
        vreg[i] = *(const u16x8*)(vT + (size_t)(h * HD + vrow[i]) * S_LEN +
                                  kbase + vcg[i] * 8);
      }
    }

    // S^T = K * Q^T (this wave's 32 keys x 32 queries), 2 chains of 4
    const unsigned short* Kb = Ks[kt & 1];
    f32x16 sacc0, sacc1;
#pragma unroll
    for (int j = 0; j < 16; j++) { sacc0[j] = 0.f; sacc1[j] = 0.f; }
    __builtin_amdgcn_s_setprio(1);
#pragma unroll
    for (int ks = 0; ks < 4; ks++) {
      const bf16x8 kf0 = *(const bf16x8*)(Kb + kfo[ks]);
      const bf16x8 kf1 = *(const bf16x8*)(Kb + kfo[ks + 4]);
      sacc0 = __builtin_amdgcn_mfma_f32_32x32x16_bf16(kf0, qf[ks], sacc0, 0, 0, 0);
      sacc1 = __builtin_amdgcn_mfma_f32_32x32x16_bf16(kf1, qf[ks + 4], sacc1, 0, 0, 0);
    }
    __builtin_amdgcn_s_setprio(0);
    const f32x16 sacc = sacc0 + sacc1;

    // P = exp2(S^T) in-register; pack to PV B-fragments (cvt_pk + permlane)
    float p[16];
#pragma unroll
    for (int r = 0; r < 16; r++) p[r] = __builtin_amdgcn_exp2f(sacc[r]);
#pragma unroll
    for (int r = 0; r < 4; r++)
      lsumv[r] += (p[4 * r] + p[4 * r + 1]) + (p[4 * r + 2] + p[4 * r + 3]);

    unsigned int Aw[8];
#pragma unroll
    for (int i = 0; i < 8; i++)
      asm("v_cvt_pk_bf16_f32 %0, %1, %2"
          : "=v"(Aw[i]) : "v"(p[2 * i]), "v"(p[2 * i + 1]));
    // dst.upper <-> src.lower: {t0,t2}=swap(A0,A2) etc. (query=lane&31 kept)
    asm volatile("v_permlane32_swap_b32 %0, %1" : "+v"(Aw[0]), "+v"(Aw[2]));
    asm volatile("v_permlane32_swap_b32 %0, %1" : "+v"(Aw[1]), "+v"(Aw[3]));
    asm volatile("v_permlane32_swap_b32 %0, %1" : "+v"(Aw[4]), "+v"(Aw[6]));
    asm volatile("v_permlane32_swap_b32 %0, %1" : "+v"(Aw[5]), "+v"(Aw[7]));
    union { unsigned int wd[4]; bf16x8 v; } u0, u1;
    u0.wd[0] = Aw[0]; u0.wd[1] = Aw[1]; u0.wd[2] = Aw[2]; u0.wd[3] = Aw[3];
    u1.wd[0] = Aw[4]; u1.wd[1] = Aw[5]; u1.wd[2] = Aw[6]; u1.wd[3] = Aw[7];
    const bf16x8 pfr0 = u0.v, pfr1 = u1.v;

    // partial O^T += V^T[all dims][own keys] * P^T
    const unsigned short* Vb = Vt[kt & 1];
    __builtin_amdgcn_s_setprio(1);
#pragma unroll
    for (int mt = 0; mt < 4; mt++) {
      const bf16x8 v0 = *(const bf16x8*)(Vb + vfo[mt][0]);
      const bf16x8 v1 = *(const bf16x8*)(Vb + vfo[mt][1]);
      Oacc[mt] = __builtin_amdgcn_mfma_f32_32x32x16_bf16(v0, pfr0, Oacc[mt], 0, 0, 0);
      Oacc[mt] = __builtin_amdgcn_mfma_f32_32x32x16_bf16(v1, pfr1, Oacc[mt], 0, 0, 0);
    }
    __builtin_amdgcn_s_setprio(0);

    // stage next tile into the other buffers (WAR safe: last read pre-barrier(t-1))
    if (kt + 1 < NT) {
      unsigned short* Kn = Ks[(kt + 1) & 1];
      unsigned short* Vn = Vt[(kt + 1) & 1];
#pragma unroll
      for (int i = 0; i < 4; i++) {
        *(u16x8*)(Kn + kso[i]) = kreg[i];
        *(u16x8*)(Vn + vso[i]) = vreg[i];
      }
    }
    __syncthreads();   // single barrier: writes visible, reads drained
  }

  // ---- epilogue ----
  // l: combine lh halves, then kh pairs via Lred
  float lsum = (lsumv[0] + lsumv[1]) + (lsumv[2] + lsumv[3]);
  lsum += __shfl_xor(lsum, 32);
  if (lh == 0) Lred[w][l32] = lsum;

  // O: kh=1 waves dump partials (fp32) into Ks area
  float* Of = (float*)(&Ks[0][0]);   // 2*4096 floats = 32KB <= 34.8KB
  if (kh == 1) {
#pragma unroll
    for (int mt = 0; mt < 4; mt++)
#pragma unroll
      for (int r = 0; r < 16; r++)
        Of[qh * 4096 + mt * 1024 + r * 64 + lh * 32 + l32] = Oacc[mt][r];
  }
  __syncthreads();

  // kh=0 waves: add partner partial, normalize, write transpose buffer
  unsigned short* Tb = &Vt[0][0];    // 64x136 shorts = 17.4KB <= 36.9KB
  if (kh == 0) {
    const float ltot = Lred[qh * 2][l32] + Lred[qh * 2 + 1][l32];
    const float inv = 1.0f / ltot;
#pragma unroll
    for (int mt = 0; mt < 4; mt++)
#pragma unroll
      for (int rq = 0; rq < 4; rq++) {
        u16x4 pk;
#pragma unroll
        for (int ri = 0; ri < 4; ri++) {
          const int r = rq * 4 + ri;
          const float v = Oacc[mt][r] +
              Of[qh * 4096 + mt * 1024 + r * 64 + lh * 32 + l32];
          pk[ri] = f2bf(v * inv);
        }
        *(u16x4*)(Tb + (qh * 32 + l32) * 136 + mt * 32 + rq * 8 + lh * 4) = pk;
      }
  }
  __syncthreads();

  // coalesced store
#pragma unroll
  for (int i = 0; i < 4; i++) {
    const int c = i * 256 + tid;
    const int row = c >> 4, ch = c & 15;
    const u16x8 vv = *(const u16x8*)(Tb + row * 136 + ch * 8);
    *(u16x8*)(o + (size_t)(q0 + row) * DMODEL + h * HD + ch * 8) = vv;
  }
}

// ---------------- launcher ----------------
extern "C" void kernel_launch(void* const* d_in, const int* in_sizes, int n_in,
                              void* d_out, int out_size, void* d_ws, size_t ws_size,
                              hipStream_t stream) {
  (void)in_sizes; (void)n_in; (void)out_size; (void)ws_size;
  const float* x  = (const float*)d_in[0];
  const float* wq = (const float*)d_in[1];
  const float* wk = (const float*)d_in[2];
  const float* wv = (const float*)d_in[3];
  const float* wo = (const float*)d_in[4];
  float* out = (float*)d_out;

  const size_t NE = (size_t)S_LEN * DMODEL;
  unsigned short* ws = (unsigned short*)d_ws;
  unsigned short* xb  = ws + 0 * NE;
  unsigned short* wqb = ws + 1 * NE;
  unsigned short* wkb = ws + 2 * NE;
  unsigned short* wvb = ws + 3 * NE;
  unsigned short* wob = ws + 4 * NE;
  unsigned short* qb  = ws + 5 * NE;
  unsigned short* kb  = ws + 6 * NE;
  unsigned short* vTb = ws + 7 * NE;
  unsigned short* ob  = ws + 8 * NE;

  const float qscale = 0.08838834764831845f * 1.4426950408889634f;

  cast_all<<<dim3(5 * 4096), dim3(256), 0, stream>>>(x, wq, wk, wv, wo, ws,
                                                     qscale);

  gemm_qkv<<<dim3(48, 16), dim3(256), 0, stream>>>(xb, wqb, wkb, wvb, qb, kb,
                                                   vTb);

  attn_kernel<<<dim3(S_LEN / 64, NHEADS), dim3(256), 0, stream>>>(qb, kb, vTb,
                                                                  ob);

  gemm_bt64<<<dim3(16, 32), dim3(256), 0, stream>>>(ob, wob, out, S_LEN,
                                                    DMODEL, DMODEL);
}

// Round 4
// 243.527 us; speedup vs baseline: 1.0339x; 1.0339x over previous
//
#include <hip/hip_runtime.h>
#include <hip/hip_bf16.h>
#include <cstdint>
#include <cstddef>

// ---------------- types ----------------
typedef __bf16 bf16x8 __attribute__((ext_vector_type(8)));
typedef float f32x4 __attribute__((ext_vector_type(4)));
typedef float f32x16 __attribute__((ext_vector_type(16)));
typedef unsigned short u16x8 __attribute__((ext_vector_type(8)));
typedef unsigned short u16x4 __attribute__((ext_vector_type(4)));

#define S_LEN 2048
#define DMODEL 2048
#define NHEADS 16
#define HD 128

__device__ inline unsigned short f2bf(float f) {
  union { float f; unsigned int u; } v; v.f = f;
  unsigned int r = (v.u + 0x7fffu + ((v.u >> 16) & 1u)) >> 16;
  return (unsigned short)r;
}

// async global->LDS, 16B per lane; LDS dest = wave-uniform base + lane*16
__device__ __forceinline__ void gload16(const unsigned short* g,
                                        unsigned short* lds) {
  __builtin_amdgcn_global_load_lds(
      (const __attribute__((address_space(1))) void*)g,
      (__attribute__((address_space(3))) void*)lds, 16, 0, 0);
}

// ---------------- fused cast fp32 -> bf16 (all 5 matrices, 1 dispatch) -----
__global__ void cast_all(const float* __restrict__ x, const float* __restrict__ wq,
                         const float* __restrict__ wk, const float* __restrict__ wv,
                         const float* __restrict__ wo,
                         unsigned short* __restrict__ out, float qscale) {
  const int b = blockIdx.x;
  const int seg = b >> 12;                       // 4096 blocks per segment
  const int i = ((b & 4095) * 256 + threadIdx.x) * 4;
  const float* src = seg == 0 ? x : seg == 1 ? wq : seg == 2 ? wk
                   : seg == 3 ? wv : wo;
  const float scale = (seg == 1) ? qscale : 1.0f;
  unsigned short* dst = out + (size_t)seg * ((size_t)S_LEN * DMODEL);
  float4 v = *(const float4*)(src + i);
  u16x4 o;
  o.x = f2bf(v.x * scale); o.y = f2bf(v.y * scale);
  o.z = f2bf(v.z * scale); o.w = f2bf(v.w * scale);
  *(u16x4*)(dst + i) = o;
}

// ---------------- GEMM core: C[M,N] = A[M,K] * B[N,K]^T (bf16, fp32 acc) ---
// BK=64, XOR column-chunk swizzle staging.
// MODE 1: bf16 out   MODE 2: bf16 out transposed (C^T)
template <int MODE>
__device__ __forceinline__ void gemm_core64(
    const unsigned short* __restrict__ A, const unsigned short* __restrict__ B,
    unsigned short* __restrict__ Cb,
    int M, int N, int K, int m0, int n0,
    unsigned short* As, unsigned short* Bs) {
  constexpr int BK = 64;
  const int tid = threadIdx.x;
  const int wave = tid >> 6, lane = tid & 63;
  const int lg = lane >> 4, lr = lane & 15;
  const int rw = (wave >> 1) * 64;
  const int cw = (wave & 1) * 64;
  const int swz = lr & 7;

  const unsigned short* Ap[4];
  const unsigned short* Bp[4];
  unsigned short *as[4], *bs[4];
#pragma unroll
  for (int j = 0; j < 4; j++) {
    const int cc = j * 256 + tid;
    const int row = cc >> 3;
    const int col8 = (cc & 7) ^ (row & 7);       // XOR swizzle
    Ap[j] = A + (size_t)(m0 + row) * K + col8 * 8;
    Bp[j] = B + (size_t)(n0 + row) * K + col8 * 8;
    as[j] = As + j * 2048 + wave * 512;
    bs[j] = Bs + j * 2048 + wave * 512;
  }

  f32x4 acc[4][4];
#pragma unroll
  for (int i = 0; i < 4; i++)
#pragma unroll
    for (int j = 0; j < 4; j++) acc[i][j] = (f32x4){0.f, 0.f, 0.f, 0.f};

  const int nk = K / BK;
  for (int kt = 0; kt < nk; ++kt) {
    const int ko = kt * BK;
    __syncthreads();
#pragma unroll
    for (int j = 0; j < 4; j++) {
      gload16(Ap[j] + ko, as[j]);
      gload16(Bp[j] + ko, bs[j]);
    }
    __syncthreads();

#pragma unroll
    for (int kk = 0; kk < 2; kk++) {
      bf16x8 af[4], bfr[4];
#pragma unroll
      for (int mt = 0; mt < 4; mt++)
        af[mt] = *(const bf16x8*)(As + (rw + mt * 16 + lr) * 64 +
                                  (((kk * 4 + lg) ^ swz) * 8));
#pragma unroll
      for (int nt = 0; nt < 4; nt++)
        bfr[nt] = *(const bf16x8*)(Bs + (cw + nt * 16 + lr) * 64 +
                                   (((kk * 4 + lg) ^ swz) * 8));
#pragma unroll
      for (int mt = 0; mt < 4; mt++)
#pragma unroll
        for (int nt = 0; nt < 4; nt++)
          acc[mt][nt] = __builtin_amdgcn_mfma_f32_16x16x32_bf16(
              af[mt], bfr[nt], acc[mt][nt], 0, 0, 0);
    }
  }

#pragma unroll
  for (int mt = 0; mt < 4; mt++)
#pragma unroll
    for (int nt = 0; nt < 4; nt++) {
      const int col = n0 + cw + nt * 16 + lr;
#pragma unroll
      for (int r = 0; r < 4; r++) {
        const int row = m0 + rw + mt * 16 + lg * 4 + r;
        const float v = acc[mt][nt][r];
        if (MODE == 1) Cb[(size_t)row * N + col] = f2bf(v);
        else Cb[(size_t)col * M + row] = f2bf(v);
      }
    }
}

// fused Q/K/V projection: grid (48, 16); blockIdx.x>>4 selects weight/output
__global__ __launch_bounds__(256, 2) void gemm_qkv(
    const unsigned short* __restrict__ xb, const unsigned short* __restrict__ wqb,
    const unsigned short* __restrict__ wkb, const unsigned short* __restrict__ wvb,
    unsigned short* __restrict__ qb, unsigned short* __restrict__ kb,
    unsigned short* __restrict__ vTb) {
  __shared__ unsigned short As[128 * 64];
  __shared__ unsigned short Bs[128 * 64];
  const int which = blockIdx.x >> 4;             // block-uniform
  const int n0 = (blockIdx.x & 15) * 128;
  const int m0 = blockIdx.y * 128;
  if (which == 0)
    gemm_core64<1>(xb, wqb, qb, S_LEN, DMODEL, DMODEL, m0, n0, As, Bs);
  else if (which == 1)
    gemm_core64<1>(xb, wkb, kb, S_LEN, DMODEL, DMODEL, m0, n0, As, Bs);
  else
    gemm_core64<2>(xb, wvb, vTb, S_LEN, DMODEL, DMODEL, m0, n0, As, Bs);
}

// ---------------- O-projection GEMM, 64x128 tile, BK=128, fp32 out --------
__global__ __launch_bounds__(256, 2) void gemm_bt64(
    const unsigned short* __restrict__ A, const unsigned short* __restrict__ B,
    float* __restrict__ Cf, int M, int N, int K) {
  constexpr int BK = 128;
  __shared__ unsigned short As[64 * 128];
  __shared__ unsigned short Bs[128 * 128];
  const int tid = threadIdx.x;
  const int wave = tid >> 6, lane = tid & 63;
  const int lg = lane >> 4, lr = lane & 15;
  const int rw = (wave >> 1) * 32;
  const int cw = (wave & 1) * 64;
  const int m0 = blockIdx.y * 64, n0 = blockIdx.x * 128;
  const int swz = lr & 7;

  const unsigned short* Ap[4];
  const unsigned short* Bp[8];
  unsigned short *as[4], *bs[8];
#pragma unroll
  for (int j = 0; j < 4; j++) {
    const int cc = j * 256 + tid;
    const int row = cc >> 4;
    const int col16 = (cc & 15) ^ (row & 7);
    Ap[j] = A + (size_t)(m0 + row) * K + col16 * 8;
    as[j] = As + j * 2048 + wave * 512;
  }
#pragma unroll
  for (int j = 0; j < 8; j++) {
    const int cc = j * 256 + tid;
    const int row = cc >> 4;
    const int col16 = (cc & 15) ^ (row & 7);
    Bp[j] = B + (size_t)(n0 + row) * K + col16 * 8;
    bs[j] = Bs + j * 2048 + wave * 512;
  }

  f32x4 acc[2][4];
#pragma unroll
  for (int i = 0; i < 2; i++)
#pragma unroll
    for (int j = 0; j < 4; j++) acc[i][j] = (f32x4){0.f, 0.f, 0.f, 0.f};

  const int nk = K / BK;
  for (int kt = 0; kt < nk; ++kt) {
    const int ko = kt * BK;
    __syncthreads();
#pragma unroll
    for (int j = 0; j < 4; j++) gload16(Ap[j] + ko, as[j]);
#pragma unroll
    for (int j = 0; j < 8; j++) gload16(Bp[j] + ko, bs[j]);
    __syncthreads();

#pragma unroll
    for (int kk = 0; kk < 4; kk++) {
      bf16x8 af[2], bfr[4];
#pragma unroll
      for (int mt = 0; mt < 2; mt++)
        af[mt] = *(const bf16x8*)(As + (rw + mt * 16 + lr) * 128 +
                                  (((kk * 4 + lg) ^ swz) * 8));
#pragma unroll
      for (int nt = 0; nt < 4; nt++)
        bfr[nt] = *(const bf16x8*)(Bs + (cw + nt * 16 + lr) * 128 +
                                   (((kk * 4 + lg) ^ swz) * 8));
#pragma unroll
      for (int mt = 0; mt < 2; mt++)
#pragma unroll
        for (int nt = 0; nt < 4; nt++)
          acc[mt][nt] = __builtin_amdgcn_mfma_f32_16x16x32_bf16(
              af[mt], bfr[nt], acc[mt][nt], 0, 0, 0);
    }
  }

#pragma unroll
  for (int mt = 0; mt < 2; mt++)
#pragma unroll
    for (int nt = 0; nt < 4; nt++) {
      const int col = n0 + cw + nt * 16 + lr;
#pragma unroll
      for (int r = 0; r < 4; r++) {
        const int row = m0 + rw + mt * 16 + lg * 4 + r;
        Cf[(size_t)row * N + col] = acc[mt][nt][r];
      }
    }
}

// ---------------- flash attention, round 9: in-register P, 1 barrier/tile --
// Round-8 structure kept; round-8 XOR chunk swizzle REVERTED (it composed
// with the odd-chunk-stride padding's built-in spread and CREATED 14.8M
// bank conflicts). With stride 136 shorts (17x16B) and 72 shorts (9x16B),
// bank group = (row + chunk) mod 8 -- already uniform for every access
// pattern in this kernel; no swizzle needed.
// S^T = K*Q^T per wave (32 keys x 32 queries, key axis register-local).
// P = exp2(S^T) stays IN REGISTER: v_cvt_pk_bf16_f32 pairs + v_permlane32_swap
// redistribute P across the lh halves into exact PV B-fragments (T12).
// Each wave accumulates a PARTIAL O^T over its own 32-key half across all
// 128 dims; the two kh-halves are summed once in the epilogue via LDS.
// Ks and Vt both double-buffered -> ONE barrier per tile; staging global
// loads issued at tile top, LDS writes at tile end (full-tile latency slack).
__global__ __launch_bounds__(256, 2) void attn_kernel(
    const unsigned short* __restrict__ q, const unsigned short* __restrict__ k,
    const unsigned short* __restrict__ vT, unsigned short* __restrict__ o) {
  constexpr int KT = 64;
  __shared__ unsigned short Ks[2][64 * 136];  // dbuf [key][dim: 16 chunks + pad]
  __shared__ unsigned short Vt[2][128 * 72];  // dbuf [dim][key: 8 chunks + pad]
  __shared__ float Lred[4][32];

  const int tid = threadIdx.x;
  const int w = tid >> 6, lane = tid & 63;
  const int l32 = lane & 31, lh = lane >> 5;
  const int qh = w >> 1;     // query half
  const int kh = w & 1;      // key half (S^T and PV partial)
  const int h = blockIdx.y;
  const int q0 = blockIdx.x * 64;

  // Q as B-fragments in registers: B[k=d][n=q]
  bf16x8 qf[8];
#pragma unroll
  for (int ks = 0; ks < 8; ks++)
    qf[ks] = *(const bf16x8*)(q + (size_t)(q0 + qh * 32 + l32) * DMODEL +
                              h * HD + ks * 16 + lh * 8);

  // partial O^T over this wave's key half: [mt 4 dims-of-32][16 regs]
  f32x16 Oacc[4];
#pragma unroll
  for (int mt = 0; mt < 4; mt++)
#pragma unroll
    for (int j = 0; j < 16; j++) Oacc[mt][j] = 0.f;
  f32x4 lsumv = (f32x4){0.f, 0.f, 0.f, 0.f};

  // staging coordinates (natural padded layout, no swizzle)
  int krow[4], kcg[4], vrow[4], vcg[4], kso[4], vso[4];
#pragma unroll
  for (int i = 0; i < 4; i++) {
    const int c = i * 256 + tid;
    krow[i] = c >> 4; kcg[i] = c & 15;
    vrow[i] = c >> 3; vcg[i] = c & 7;
    kso[i] = krow[i] * 136 + kcg[i] * 8;
    vso[i] = vrow[i] * 72 + vcg[i] * 8;
  }

  // LDS read offsets (loop-invariant, natural layout)
  int kfo[8];
#pragma unroll
  for (int ks = 0; ks < 8; ks++)
    kfo[ks] = (kh * 32 + l32) * 136 + (ks * 2 + lh) * 8;
  int vfo[4][2];
#pragma unroll
  for (int mt = 0; mt < 4; mt++)
#pragma unroll
    for (int s = 0; s < 2; s++)
      vfo[mt][s] = (mt * 32 + l32) * 72 + (kh * 4 + s * 2 + lh) * 8;

  // prologue: tile 0 -> regs -> LDS[0]
  u16x8 kreg[4], vreg[4];
#pragma unroll
  for (int i = 0; i < 4; i++) {
    kreg[i] = *(const u16x8*)(k + (size_t)(krow[i]) * DMODEL + h * HD + kcg[i] * 8);
    vreg[i] = *(const u16x8*)(vT + (size_t)(h * HD + vrow[i]) * S_LEN + vcg[i] * 8);
  }
#pragma unroll
  for (int i = 0; i < 4; i++) {
    *(u16x8*)(Ks[0] + kso[i]) = kreg[i];
    *(u16x8*)(Vt[0] + vso[i]) = vreg[i];
  }
  __syncthreads();

  constexpr int NT = S_LEN / KT;
  for (int kt = 0; kt < NT; ++kt) {
    // issue next-tile global loads (consumed at tile end -> full-tile slack)
    if (kt + 1 < NT) {
      const int kbase = (kt + 1) * KT;
#pragma unroll
      for (int i = 0; i < 4; i++) {
        kreg[i] = *(const u16x8*)(k + (size_t)(kbase + krow[i]) * DMODEL +
                                  h * HD + kcg[i] * 8);
        vreg[i] = *(const u16x8*)(vT + (size_t)(h * HD + vrow[i]) * S_LEN +
                                  kbase + vcg[i] * 8);
      }
    }

    // S^T = K * Q^T (this wave's 32 keys x 32 queries), 2 chains of 4
    const unsigned short* Kb = Ks[kt & 1];
    f32x16 sacc0, sacc1;
#pragma unroll
    for (int j = 0; j < 16; j++) { sacc0[j] = 0.f; sacc1[j] = 0.f; }
    __builtin_amdgcn_s_setprio(1);
#pragma unroll
    for (int ks = 0; ks < 4; ks++) {
      const bf16x8 kf0 = *(const bf16x8*)(Kb + kfo[ks]);
      const bf16x8 kf1 = *(const bf16x8*)(Kb + kfo[ks + 4]);
      sacc0 = __builtin_amdgcn_mfma_f32_32x32x16_bf16(kf0, qf[ks], sacc0, 0, 0, 0);
      sacc1 = __builtin_amdgcn_mfma_f32_32x32x16_bf16(kf1, qf[ks + 4], sacc1, 0, 0, 0);
    }
    __builtin_amdgcn_s_setprio(0);
    const f32x16 sacc = sacc0 + sacc1;

    // P = exp2(S^T) in-register; pack to PV B-fragments (cvt_pk + permlane)
    float p[16];
#pragma unroll
    for (int r = 0; r < 16; r++) p[r] = __builtin_amdgcn_exp2f(sacc[r]);
#pragma unroll
    for (int r = 0; r < 4; r++)
      lsumv[r] += (p[4 * r] + p[4 * r + 1]) + (p[4 * r + 2] + p[4 * r + 3]);

    unsigned int Aw[8];
#pragma unroll
    for (int i = 0; i < 8; i++)
      asm("v_cvt_pk_bf16_f32 %0, %1, %2"
          : "=v"(Aw[i]) : "v"(p[2 * i]), "v"(p[2 * i + 1]));
    // dst.upper <-> src.lower: {t0,t2}=swap(A0,A2) etc. (query=lane&31 kept)
    asm volatile("v_permlane32_swap_b32 %0, %1" : "+v"(Aw[0]), "+v"(Aw[2]));
    asm volatile("v_permlane32_swap_b32 %0, %1" : "+v"(Aw[1]), "+v"(Aw[3]));
    asm volatile("v_permlane32_swap_b32 %0, %1" : "+v"(Aw[4]), "+v"(Aw[6]));
    asm volatile("v_permlane32_swap_b32 %0, %1" : "+v"(Aw[5]), "+v"(Aw[7]));
    union { unsigned int wd[4]; bf16x8 v; } u0, u1;
    u0.wd[0] = Aw[0]; u0.wd[1] = Aw[1]; u0.wd[2] = Aw[2]; u0.wd[3] = Aw[3];
    u1.wd[0] = Aw[4]; u1.wd[1] = Aw[5]; u1.wd[2] = Aw[6]; u1.wd[3] = Aw[7];
    const bf16x8 pfr0 = u0.v, pfr1 = u1.v;

    // partial O^T += V^T[all dims][own keys] * P^T
    const unsigned short* Vb = Vt[kt & 1];
    __builtin_amdgcn_s_setprio(1);
#pragma unroll
    for (int mt = 0; mt < 4; mt++) {
      const bf16x8 v0 = *(const bf16x8*)(Vb + vfo[mt][0]);
      const bf16x8 v1 = *(const bf16x8*)(Vb + vfo[mt][1]);
      Oacc[mt] = __builtin_amdgcn_mfma_f32_32x32x16_bf16(v0, pfr0, Oacc[mt], 0, 0, 0);
      Oacc[mt] = __builtin_amdgcn_mfma_f32_32x32x16_bf16(v1, pfr1, Oacc[mt], 0, 0, 0);
    }
    __builtin_amdgcn_s_setprio(0);

    // stage next tile into the other buffers (WAR safe: last read pre-barrier(t-1))
    if (kt + 1 < NT) {
      unsigned short* Kn = Ks[(kt + 1) & 1];
      unsigned short* Vn = Vt[(kt + 1) & 1];
#pragma unroll
      for (int i = 0; i < 4; i++) {
        *(u16x8*)(Kn + kso[i]) = kreg[i];
        *(u16x8*)(Vn + vso[i]) = vreg[i];
      }
    }
    __syncthreads();   // single barrier: writes visible, reads drained
  }

  // ---- epilogue ----
  // l: combine lh halves, then kh pairs via Lred
  float lsum = (lsumv[0] + lsumv[1]) + (lsumv[2] + lsumv[3]);
  lsum += __shfl_xor(lsum, 32);
  if (lh == 0) Lred[w][l32] = lsum;

  // O: kh=1 waves dump partials (fp32) into Ks area
  float* Of = (float*)(&Ks[0][0]);   // 2*4096 floats = 32KB
  if (kh == 1) {
#pragma unroll
    for (int mt = 0; mt < 4; mt++)
#pragma unroll
      for (int r = 0; r < 16; r++)
        Of[qh * 4096 + mt * 1024 + r * 64 + lh * 32 + l32] = Oacc[mt][r];
  }
  __syncthreads();

  // kh=0 waves: add partner partial, normalize, write transpose buffer
  unsigned short* Tb = &Vt[0][0];    // 64x136 shorts = 17.4KB
  if (kh == 0) {
    const float ltot = Lred[qh * 2][l32] + Lred[qh * 2 + 1][l32];
    const float inv = 1.0f / ltot;
#pragma unroll
    for (int mt = 0; mt < 4; mt++)
#pragma unroll
      for (int rq = 0; rq < 4; rq++) {
        u16x4 pk;
#pragma unroll
        for (int ri = 0; ri < 4; ri++) {
          const int r = rq * 4 + ri;
          const float v = Oacc[mt][r] +
              Of[qh * 4096 + mt * 1024 + r * 64 + lh * 32 + l32];
          pk[ri] = f2bf(v * inv);
        }
        *(u16x4*)(Tb + (qh * 32 + l32) * 136 + mt * 32 + rq * 8 + lh * 4) = pk;
      }
  }
  __syncthreads();

  // coalesced store
#pragma unroll
  for (int i = 0; i < 4; i++) {
    const int c = i * 256 + tid;
    const int row = c >> 4, ch = c & 15;
    const u16x8 vv = *(const u16x8*)(Tb + row * 136 + ch * 8);
    *(u16x8*)(o + (size_t)(q0 + row) * DMODEL + h * HD + ch * 8) = vv;
  }
}

// ---------------- launcher ----------------
extern "C" void kernel_launch(void* const* d_in, const int* in_sizes, int n_in,
                              void* d_out, int out_size, void* d_ws, size_t ws_size,
                              hipStream_t stream) {
  (void)in_sizes; (void)n_in; (void)out_size; (void)ws_size;
  const float* x  = (const float*)d_in[0];
  const float* wq = (const float*)d_in[1];
  const float* wk = (const float*)d_in[2];
  const float* wv = (const float*)d_in[3];
  const float* wo = (const float*)d_in[4];
  float* out = (float*)d_out;

  const size_t NE = (size_t)S_LEN * DMODEL;
  unsigned short* ws = (unsigned short*)d_ws;
  unsigned short* xb  = ws + 0 * NE;
  unsigned short* wqb = ws + 1 * NE;
  unsigned short* wkb = ws + 2 * NE;
  unsigned short* wvb = ws + 3 * NE;
  unsigned short* wob = ws + 4 * NE;
  unsigned short* qb  = ws + 5 * NE;
  unsigned short* kb  = ws + 6 * NE;
  unsigned short* vTb = ws + 7 * NE;
  unsigned short* ob  = ws + 8 * NE;

  const float qscale = 0.08838834764831845f * 1.4426950408889634f;

  cast_all<<<dim3(5 * 4096), dim3(256), 0, stream>>>(x, wq, wk, wv, wo, ws,
                                                     qscale);

  gemm_qkv<<<dim3(48, 16), dim3(256), 0, stream>>>(xb, wqb, wkb, wvb, qb, kb,
                                                   vTb);

  attn_kernel<<<dim3(S_LEN / 64, NHEADS), dim3(256), 0, stream>>>(qb, kb, vTb,
                                                                  ob);

  gemm_bt64<<<dim3(16, 32), dim3(256), 0, stream>>>(ob, wob, out, S_LEN,
                                                    DMODEL, DMODEL);
}

// Round 5
// 242.121 us; speedup vs baseline: 1.0399x; 1.0058x over previous
//
#include <hip/hip_runtime.h>
#include <hip/hip_bf16.h>
#include <cstdint>
#include <cstddef>

// ---------------- types ----------------
typedef __bf16 bf16x8 __attribute__((ext_vector_type(8)));
typedef float f32x4 __attribute__((ext_vector_type(4)));
typedef float f32x16 __attribute__((ext_vector_type(16)));
typedef unsigned short u16x8 __attribute__((ext_vector_type(8)));
typedef unsigned short u16x4 __attribute__((ext_vector_type(4)));

#define S_LEN 2048
#define DMODEL 2048
#define NHEADS 16
#define HD 128

__device__ inline unsigned short f2bf(float f) {
  union { float f; unsigned int u; } v; v.f = f;
  unsigned int r = (v.u + 0x7fffu + ((v.u >> 16) & 1u)) >> 16;
  return (unsigned short)r;
}

// async global->LDS, 16B per lane; LDS dest = wave-uniform base + lane*16
__device__ __forceinline__ void gload16(const unsigned short* g,
                                        unsigned short* lds) {
  __builtin_amdgcn_global_load_lds(
      (const __attribute__((address_space(1))) void*)g,
      (__attribute__((address_space(3))) void*)lds, 16, 0, 0);
}

// ---------------- fused cast fp32 -> bf16 (all 5 matrices, 1 dispatch) -----
__global__ void cast_all(const float* __restrict__ x, const float* __restrict__ wq,
                         const float* __restrict__ wk, const float* __restrict__ wv,
                         const float* __restrict__ wo,
                         unsigned short* __restrict__ out, float qscale) {
  const int b = blockIdx.x;
  const int seg = b >> 12;                       // 4096 blocks per segment
  const int i = ((b & 4095) * 256 + threadIdx.x) * 4;
  const float* src = seg == 0 ? x : seg == 1 ? wq : seg == 2 ? wk
                   : seg == 3 ? wv : wo;
  const float scale = (seg == 1) ? qscale : 1.0f;
  unsigned short* dst = out + (size_t)seg * ((size_t)S_LEN * DMODEL);
  float4 v = *(const float4*)(src + i);
  u16x4 o;
  o.x = f2bf(v.x * scale); o.y = f2bf(v.y * scale);
  o.z = f2bf(v.z * scale); o.w = f2bf(v.w * scale);
  *(u16x4*)(dst + i) = o;
}

// ---------------- GEMM core: C[M,N] = A[M,K] * B[N,K]^T (bf16, fp32 acc) ---
// BK=64, XOR column-chunk swizzle staging (SQ_LDS_BANK_CONFLICT = 0, HW-verified).
// MODE 1: bf16 out   MODE 2: bf16 out transposed (C^T)
template <int MODE>
__device__ __forceinline__ void gemm_core64(
    const unsigned short* __restrict__ A, const unsigned short* __restrict__ B,
    unsigned short* __restrict__ Cb,
    int M, int N, int K, int m0, int n0,
    unsigned short* As, unsigned short* Bs) {
  constexpr int BK = 64;
  const int tid = threadIdx.x;
  const int wave = tid >> 6, lane = tid & 63;
  const int lg = lane >> 4, lr = lane & 15;
  const int rw = (wave >> 1) * 64;
  const int cw = (wave & 1) * 64;
  const int swz = lr & 7;

  const unsigned short* Ap[4];
  const unsigned short* Bp[4];
  unsigned short *as[4], *bs[4];
#pragma unroll
  for (int j = 0; j < 4; j++) {
    const int cc = j * 256 + tid;
    const int row = cc >> 3;
    const int col8 = (cc & 7) ^ (row & 7);       // XOR swizzle
    Ap[j] = A + (size_t)(m0 + row) * K + col8 * 8;
    Bp[j] = B + (size_t)(n0 + row) * K + col8 * 8;
    as[j] = As + j * 2048 + wave * 512;
    bs[j] = Bs + j * 2048 + wave * 512;
  }

  f32x4 acc[4][4];
#pragma unroll
  for (int i = 0; i < 4; i++)
#pragma unroll
    for (int j = 0; j < 4; j++) acc[i][j] = (f32x4){0.f, 0.f, 0.f, 0.f};

  const int nk = K / BK;
  for (int kt = 0; kt < nk; ++kt) {
    const int ko = kt * BK;
    __syncthreads();
#pragma unroll
    for (int j = 0; j < 4; j++) {
      gload16(Ap[j] + ko, as[j]);
      gload16(Bp[j] + ko, bs[j]);
    }
    __syncthreads();

#pragma unroll
    for (int kk = 0; kk < 2; kk++) {
      bf16x8 af[4], bfr[4];
#pragma unroll
      for (int mt = 0; mt < 4; mt++)
        af[mt] = *(const bf16x8*)(As + (rw + mt * 16 + lr) * 64 +
                                  (((kk * 4 + lg) ^ swz) * 8));
#pragma unroll
      for (int nt = 0; nt < 4; nt++)
        bfr[nt] = *(const bf16x8*)(Bs + (cw + nt * 16 + lr) * 64 +
                                   (((kk * 4 + lg) ^ swz) * 8));
#pragma unroll
      for (int mt = 0; mt < 4; mt++)
#pragma unroll
        for (int nt = 0; nt < 4; nt++)
          acc[mt][nt] = __builtin_amdgcn_mfma_f32_16x16x32_bf16(
              af[mt], bfr[nt], acc[mt][nt], 0, 0, 0);
    }
  }

#pragma unroll
  for (int mt = 0; mt < 4; mt++)
#pragma unroll
    for (int nt = 0; nt < 4; nt++) {
      const int col = n0 + cw + nt * 16 + lr;
#pragma unroll
      for (int r = 0; r < 4; r++) {
        const int row = m0 + rw + mt * 16 + lg * 4 + r;
        const float v = acc[mt][nt][r];
        if (MODE == 1) Cb[(size_t)row * N + col] = f2bf(v);
        else Cb[(size_t)col * M + row] = f2bf(v);
      }
    }
}

// fused Q/K/V projection: grid (48, 16); blockIdx.x>>4 selects weight/output
// Round-10: __launch_bounds__(256,3). Grid 768 = exactly 3 blocks/CU
// (LDS 32KB*3=96KB, VGPR 72 < 168 cap). At (256,2) only 512 of 768 blocks
// were co-resident -> 256-block half-occupancy tail + less cross-block
// overlap for the serial stage->compute loop (m97's 912 TF was at 3/CU).
__global__ __launch_bounds__(256, 3) void gemm_qkv(
    const unsigned short* __restrict__ xb, const unsigned short* __restrict__ wqb,
    const unsigned short* __restrict__ wkb, const unsigned short* __restrict__ wvb,
    unsigned short* __restrict__ qb, unsigned short* __restrict__ kb,
    unsigned short* __restrict__ vTb) {
  __shared__ unsigned short As[128 * 64];
  __shared__ unsigned short Bs[128 * 64];
  const int which = blockIdx.x >> 4;             // block-uniform
  const int n0 = (blockIdx.x & 15) * 128;
  const int m0 = blockIdx.y * 128;
  if (which == 0)
    gemm_core64<1>(xb, wqb, qb, S_LEN, DMODEL, DMODEL, m0, n0, As, Bs);
  else if (which == 1)
    gemm_core64<1>(xb, wkb, kb, S_LEN, DMODEL, DMODEL, m0, n0, As, Bs);
  else
    gemm_core64<2>(xb, wvb, vTb, S_LEN, DMODEL, DMODEL, m0, n0, As, Bs);
}

// ---------------- O-projection GEMM, 64x128 tile, BK=128, fp32 out --------
// grid 512 = 2/CU exact (no tail); 48KB LDS.
__global__ __launch_bounds__(256, 2) void gemm_bt64(
    const unsigned short* __restrict__ A, const unsigned short* __restrict__ B,
    float* __restrict__ Cf, int M, int N, int K) {
  constexpr int BK = 128;
  __shared__ unsigned short As[64 * 128];
  __shared__ unsigned short Bs[128 * 128];
  const int tid = threadIdx.x;
  const int wave = tid >> 6, lane = tid & 63;
  const int lg = lane >> 4, lr = lane & 15;
  const int rw = (wave >> 1) * 32;
  const int cw = (wave & 1) * 64;
  const int m0 = blockIdx.y * 64, n0 = blockIdx.x * 128;
  const int swz = lr & 7;

  const unsigned short* Ap[4];
  const unsigned short* Bp[8];
  unsigned short *as[4], *bs[8];
#pragma unroll
  for (int j = 0; j < 4; j++) {
    const int cc = j * 256 + tid;
    const int row = cc >> 4;
    const int col16 = (cc & 15) ^ (row & 7);
    Ap[j] = A + (size_t)(m0 + row) * K + col16 * 8;
    as[j] = As + j * 2048 + wave * 512;
  }
#pragma unroll
  for (int j = 0; j < 8; j++) {
    const int cc = j * 256 + tid;
    const int row = cc >> 4;
    const int col16 = (cc & 15) ^ (row & 7);
    Bp[j] = B + (size_t)(n0 + row) * K + col16 * 8;
    bs[j] = Bs + j * 2048 + wave * 512;
  }

  f32x4 acc[2][4];
#pragma unroll
  for (int i = 0; i < 2; i++)
#pragma unroll
    for (int j = 0; j < 4; j++) acc[i][j] = (f32x4){0.f, 0.f, 0.f, 0.f};

  const int nk = K / BK;
  for (int kt = 0; kt < nk; ++kt) {
    const int ko = kt * BK;
    __syncthreads();
#pragma unroll
    for (int j = 0; j < 4; j++) gload16(Ap[j] + ko, as[j]);
#pragma unroll
    for (int j = 0; j < 8; j++) gload16(Bp[j] + ko, bs[j]);
    __syncthreads();

#pragma unroll
    for (int kk = 0; kk < 4; kk++) {
      bf16x8 af[2], bfr[4];
#pragma unroll
      for (int mt = 0; mt < 2; mt++)
        af[mt] = *(const bf16x8*)(As + (rw + mt * 16 + lr) * 128 +
                                  (((kk * 4 + lg) ^ swz) * 8));
#pragma unroll
      for (int nt = 0; nt < 4; nt++)
        bfr[nt] = *(const bf16x8*)(Bs + (cw + nt * 16 + lr) * 128 +
                                   (((kk * 4 + lg) ^ swz) * 8));
#pragma unroll
      for (int mt = 0; mt < 2; mt++)
#pragma unroll
        for (int nt = 0; nt < 4; nt++)
          acc[mt][nt] = __builtin_amdgcn_mfma_f32_16x16x32_bf16(
              af[mt], bfr[nt], acc[mt][nt], 0, 0, 0);
    }
  }

#pragma unroll
  for (int mt = 0; mt < 2; mt++)
#pragma unroll
    for (int nt = 0; nt < 4; nt++) {
      const int col = n0 + cw + nt * 16 + lr;
#pragma unroll
      for (int r = 0; r < 4; r++) {
        const int row = m0 + rw + mt * 16 + lg * 4 + r;
        Cf[(size_t)row * N + col] = acc[mt][nt][r];
      }
    }
}

// ---------------- flash attention (round-9 verified structure) ------------
// In-register P, 1 barrier/tile, per-wave partial O, dbuf Ks/Vt, natural
// padded LDS layout (odd 16B-chunk stride spreads bank groups; measured
// conflict-free). Do not re-add chunk XOR swizzle here (round-8 regression).
__global__ __launch_bounds__(256, 2) void attn_kernel(
    const unsigned short* __restrict__ q, const unsigned short* __restrict__ k,
    const unsigned short* __restrict__ vT, unsigned short* __restrict__ o) {
  constexpr int KT = 64;
  __shared__ unsigned short Ks[2][64 * 136];  // dbuf [key][dim: 16 chunks + pad]
  __shared__ unsigned short Vt[2][128 * 72];  // dbuf [dim][key: 8 chunks + pad]
  __shared__ float Lred[4][32];

  const int tid = threadIdx.x;
  const int w = tid >> 6, lane = tid & 63;
  const int l32 = lane & 31, lh = lane >> 5;
  const int qh = w >> 1;     // query half
  const int kh = w & 1;      // key half (S^T and PV partial)
  const int h = blockIdx.y;
  const int q0 = blockIdx.x * 64;

  // Q as B-fragments in registers: B[k=d][n=q]
  bf16x8 qf[8];
#pragma unroll
  for (int ks = 0; ks < 8; ks++)
    qf[ks] = *(const bf16x8*)(q + (size_t)(q0 + qh * 32 + l32) * DMODEL +
                              h * HD + ks * 16 + lh * 8);

  // partial O^T over this wave's key half: [mt 4 dims-of-32][16 regs]
  f32x16 Oacc[4];
#pragma unroll
  for (int mt = 0; mt < 4; mt++)
#pragma unroll
    for (int j = 0; j < 16; j++) Oacc[mt][j] = 0.f;
  f32x4 lsumv = (f32x4){0.f, 0.f, 0.f, 0.f};

  // staging coordinates (natural padded layout, no swizzle)
  int krow[4], kcg[4], vrow[4], vcg[4], kso[4], vso[4];
#pragma unroll
  for (int i = 0; i < 4; i++) {
    const int c = i * 256 + tid;
    krow[i] = c >> 4; kcg[i] = c & 15;
    vrow[i] = c >> 3; vcg[i] = c & 7;
    kso[i] = krow[i] * 136 + kcg[i] * 8;
    vso[i] = vrow[i] * 72 + vcg[i] * 8;
  }

  // LDS read offsets (loop-invariant, natural layout)
  int kfo[8];
#pragma unroll
  for (int ks = 0; ks < 8; ks++)
    kfo[ks] = (kh * 32 + l32) * 136 + (ks * 2 + lh) * 8;
  int vfo[4][2];
#pragma unroll
  for (int mt = 0; mt < 4; mt++)
#pragma unroll
    for (int s = 0; s < 2; s++)
      vfo[mt][s] = (mt * 32 + l32) * 72 + (kh * 4 + s * 2 + lh) * 8;

  // prologue: tile 0 -> regs -> LDS[0]
  u16x8 kreg[4], vreg[4];
#pragma unroll
  for (int i = 0; i < 4; i++) {
    kreg[i] = *(const u16x8*)(k + (size_t)(krow[i]) * DMODEL + h * HD + kcg[i] * 8);
    vreg[i] = *(const u16x8*)(vT + (size_t)(h * HD + vrow[i]) * S_LEN + vcg[i] * 8);
  }
#pragma unroll
  for (int i = 0; i < 4; i++) {
    *(u16x8*)(Ks[0] + kso[i]) = kreg[i];
    *(u16x8*)(Vt[0] + vso[i]) = vreg[i];
  }
  __syncthreads();

  constexpr int NT = S_LEN / KT;
  for (int kt = 0; kt < NT; ++kt) {
    // issue next-tile global loads (consumed at tile end -> full-tile slack)
    if (kt + 1 < NT) {
      const int kbase = (kt + 1) * KT;
#pragma unroll
      for (int i = 0; i < 4; i++) {
        kreg[i] = *(const u16x8*)(k + (size_t)(kbase + krow[i]) * DMODEL +
                                  h * HD + kcg[i] * 8);
        vreg[i] = *(const u16x8*)(vT + (size_t)(h * HD + vrow[i]) * S_LEN +
                                  kbase + vcg[i] * 8);
      }
    }

    // S^T = K * Q^T (this wave's 32 keys x 32 queries), 2 chains of 4
    const unsigned short* Kb = Ks[kt & 1];
    f32x16 sacc0, sacc1;
#pragma unroll
    for (int j = 0; j < 16; j++) { sacc0[j] = 0.f; sacc1[j] = 0.f; }
    __builtin_amdgcn_s_setprio(1);
#pragma unroll
    for (int ks = 0; ks < 4; ks++) {
      const bf16x8 kf0 = *(const bf16x8*)(Kb + kfo[ks]);
      const bf16x8 kf1 = *(const bf16x8*)(Kb + kfo[ks + 4]);
      sacc0 = __builtin_amdgcn_mfma_f32_32x32x16_bf16(kf0, qf[ks], sacc0, 0, 0, 0);
      sacc1 = __builtin_amdgcn_mfma_f32_32x32x16_bf16(kf1, qf[ks + 4], sacc1, 0, 0, 0);
    }
    __builtin_amdgcn_s_setprio(0);
    const f32x16 sacc = sacc0 + sacc1;

    // P = exp2(S^T) in-register; pack to PV B-fragments (cvt_pk + permlane)
    float p[16];
#pragma unroll
    for (int r = 0; r < 16; r++) p[r] = __builtin_amdgcn_exp2f(sacc[r]);
#pragma unroll
    for (int r = 0; r < 4; r++)
      lsumv[r] += (p[4 * r] + p[4 * r + 1]) + (p[4 * r + 2] + p[4 * r + 3]);

    unsigned int Aw[8];
#pragma unroll
    for (int i = 0; i < 8; i++)
      asm("v_cvt_pk_bf16_f32 %0, %1, %2"
          : "=v"(Aw[i]) : "v"(p[2 * i]), "v"(p[2 * i + 1]));
    // dst.upper <-> src.lower: {t0,t2}=swap(A0,A2) etc. (query=lane&31 kept)
    asm volatile("v_permlane32_swap_b32 %0, %1" : "+v"(Aw[0]), "+v"(Aw[2]));
    asm volatile("v_permlane32_swap_b32 %0, %1" : "+v"(Aw[1]), "+v"(Aw[3]));
    asm volatile("v_permlane32_swap_b32 %0, %1" : "+v"(Aw[4]), "+v"(Aw[6]));
    asm volatile("v_permlane32_swap_b32 %0, %1" : "+v"(Aw[5]), "+v"(Aw[7]));
    union { unsigned int wd[4]; bf16x8 v; } u0, u1;
    u0.wd[0] = Aw[0]; u0.wd[1] = Aw[1]; u0.wd[2] = Aw[2]; u0.wd[3] = Aw[3];
    u1.wd[0] = Aw[4]; u1.wd[1] = Aw[5]; u1.wd[2] = Aw[6]; u1.wd[3] = Aw[7];
    const bf16x8 pfr0 = u0.v, pfr1 = u1.v;

    // partial O^T += V^T[all dims][own keys] * P^T
    const unsigned short* Vb = Vt[kt & 1];
    __builtin_amdgcn_s_setprio(1);
#pragma unroll
    for (int mt = 0; mt < 4; mt++) {
      const bf16x8 v0 = *(const bf16x8*)(Vb + vfo[mt][0]);
      const bf16x8 v1 = *(const bf16x8*)(Vb + vfo[mt][1]);
      Oacc[mt] = __builtin_amdgcn_mfma_f32_32x32x16_bf16(v0, pfr0, Oacc[mt], 0, 0, 0);
      Oacc[mt] = __builtin_amdgcn_mfma_f32_32x32x16_bf16(v1, pfr1, Oacc[mt], 0, 0, 0);
    }
    __builtin_amdgcn_s_setprio(0);

    // stage next tile into the other buffers (WAR safe: last read pre-barrier(t-1))
    if (kt + 1 < NT) {
      unsigned short* Kn = Ks[(kt + 1) & 1];
      unsigned short* Vn = Vt[(kt + 1) & 1];
#pragma unroll
      for (int i = 0; i < 4; i++) {
        *(u16x8*)(Kn + kso[i]) = kreg[i];
        *(u16x8*)(Vn + vso[i]) = vreg[i];
      }
    }
    __syncthreads();   // single barrier: writes visible, reads drained
  }

  // ---- epilogue ----
  // l: combine lh halves, then kh pairs via Lred
  float lsum = (lsumv[0] + lsumv[1]) + (lsumv[2] + lsumv[3]);
  lsum += __shfl_xor(lsum, 32);
  if (lh == 0) Lred[w][l32] = lsum;

  // O: kh=1 waves dump partials (fp32) into Ks area
  float* Of = (float*)(&Ks[0][0]);   // 2*4096 floats = 32KB
  if (kh == 1) {
#pragma unroll
    for (int mt = 0; mt < 4; mt++)
#pragma unroll
      for (int r = 0; r < 16; r++)
        Of[qh * 4096 + mt * 1024 + r * 64 + lh * 32 + l32] = Oacc[mt][r];
  }
  __syncthreads();

  // kh=0 waves: add partner partial, normalize, write transpose buffer
  unsigned short* Tb = &Vt[0][0];    // 64x136 shorts = 17.4KB
  if (kh == 0) {
    const float ltot = Lred[qh * 2][l32] + Lred[qh * 2 + 1][l32];
    const float inv = 1.0f / ltot;
#pragma unroll
    for (int mt = 0; mt < 4; mt++)
#pragma unroll
      for (int rq = 0; rq < 4; rq++) {
        u16x4 pk;
#pragma unroll
        for (int ri = 0; ri < 4; ri++) {
          const int r = rq * 4 + ri;
          const float v = Oacc[mt][r] +
              Of[qh * 4096 + mt * 1024 + r * 64 + lh * 32 + l32];
          pk[ri] = f2bf(v * inv);
        }
        *(u16x4*)(Tb + (qh * 32 + l32) * 136 + mt * 32 + rq * 8 + lh * 4) = pk;
      }
  }
  __syncthreads();

  // coalesced store
#pragma unroll
  for (int i = 0; i < 4; i++) {
    const int c = i * 256 + tid;
    const int row = c >> 4, ch = c & 15;
    const u16x8 vv = *(const u16x8*)(Tb + row * 136 + ch * 8);
    *(u16x8*)(o + (size_t)(q0 + row) * DMODEL + h * HD + ch * 8) = vv;
  }
}

// ---------------- launcher ----------------
extern "C" void kernel_launch(void* const* d_in, const int* in_sizes, int n_in,
                              void* d_out, int out_size, void* d_ws, size_t ws_size,
                              hipStream_t stream) {
  (void)in_sizes; (void)n_in; (void)out_size; (void)ws_size;
  const float* x  = (const float*)d_in[0];
  const float* wq = (const float*)d_in[1];
  const float* wk = (const float*)d_in[2];
  const float* wv = (const float*)d_in[3];
  const float* wo = (const float*)d_in[4];
  float* out = (float*)d_out;

  const size_t NE = (size_t)S_LEN * DMODEL;
  unsigned short* ws = (unsigned short*)d_ws;
  unsigned short* xb  = ws + 0 * NE;
  unsigned short* wqb = ws + 1 * NE;
  unsigned short* wkb = ws + 2 * NE;
  unsigned short* wvb = ws + 3 * NE;
  unsigned short* wob = ws + 4 * NE;
  unsigned short* qb  = ws + 5 * NE;
  unsigned short* kb  = ws + 6 * NE;
  unsigned short* vTb = ws + 7 * NE;
  unsigned short* ob  = ws + 8 * NE;

  const float qscale = 0.08838834764831845f * 1.4426950408889634f;

  cast_all<<<dim3(5 * 4096), dim3(256), 0, stream>>>(x, wq, wk, wv, wo, ws,
                                                     qscale);

  gemm_qkv<<<dim3(48, 16), dim3(256), 0, stream>>>(xb, wqb, wkb, wvb, qb, kb,
                                                   vTb);

  attn_kernel<<<dim3(S_LEN / 64, NHEADS), dim3(256), 0, stream>>>(qb, kb, vTb,
                                                                  ob);

  gemm_bt64<<<dim3(16, 32), dim3(256), 0, stream>>>(ob, wob, out, S_LEN,
                                                    DMODEL, DMODEL);
}